// Round 2
// baseline (124.244 us; speedup 1.0000x reference)
//
#include <hip/hip_runtime.h>
#include <hip/hip_bf16.h>

#define B_ 8
#define SPREV 4095
#define S_ 4096
#define E_ 2048
#define H_ 16
#define HD_ 128
#define LOW_ 512
#define NCH 64      // attention s-chunks per batch
#define CHK 64      // positions per chunk

typedef short s8v __attribute__((ext_vector_type(8)));
typedef float f4v __attribute__((ext_vector_type(4)));

__device__ __forceinline__ unsigned short f2bf(float f) {
  union { float f; unsigned u; } v; v.f = f;
  unsigned r = (v.u + 0x7fffu + ((v.u >> 16) & 1u)) >> 16;
  return (unsigned short)r;
}
__device__ __forceinline__ float bf2f(unsigned short h) {
  union { unsigned u; float f; } v; v.u = ((unsigned)h) << 16;
  return v.f;
}

// out[b][n] += sum_k x[b][k] * W[k][n], k in [k0, k0+64). Up to 3 column
// segments (separate W/out), each N a multiple of 128. atomicAdd into out.
__global__ __launch_bounds__(128) void matvec8(
    const float* __restrict__ x, int K,
    const float* __restrict__ W0, int N0, float* __restrict__ o0,
    const float* __restrict__ W1, int N1, float* __restrict__ o1,
    const float* __restrict__ W2, int N2, float* __restrict__ o2)
{
  int cb = blockIdx.x;
  int nb0 = N0 >> 7, nb1 = N1 >> 7;
  const float* W; float* o; int N, colbase;
  if (cb < nb0)            { W = W0; o = o0; N = N0; colbase = cb << 7; }
  else if (cb < nb0 + nb1) { W = W1; o = o1; N = N1; colbase = (cb - nb0) << 7; }
  else                     { W = W2; o = o2; N = N2; colbase = (cb - nb0 - nb1) << 7; }
  int col = colbase + threadIdx.x;
  int k0 = blockIdx.y * 64;
  float acc[B_];
  #pragma unroll
  for (int b = 0; b < B_; ++b) acc[b] = 0.f;
  const float* Wp = W + (size_t)k0 * N + col;
  #pragma unroll 4
  for (int k = 0; k < 64; ++k) {
    float wv = Wp[(size_t)k * N];
    #pragma unroll
    for (int b = 0; b < B_; ++b)
      acc[b] = fmaf(x[b * K + k0 + k], wv, acc[b]);   // uniform -> s_load
  }
  #pragma unroll
  for (int b = 0; b < B_; ++b) atomicAdd(&o[b * N + col], acc[b]);
}

// qeff[b,h,l] = sum_d FU[l, h*128+d] * Qc[b, h*128+d]   (write bf16)
__global__ __launch_bounds__(128) void qeff_kernel(
    const float* __restrict__ Qc, const float* __restrict__ FU,
    unsigned short* __restrict__ qeff)
{
  int h = blockIdx.x, b = blockIdx.y, t = threadIdx.x;
  __shared__ float qs[HD_];
  qs[t] = Qc[b * E_ + h * HD_ + t];
  __syncthreads();
  const f4v* q4 = (const f4v*)qs;
  #pragma unroll
  for (int li = 0; li < 4; ++li) {
    int l = t + li * 128;
    const f4v* w4 = (const f4v*)(FU + (size_t)l * (2 * E_) + h * HD_);
    float a = 0.f;
    #pragma unroll 8
    for (int d4 = 0; d4 < 32; ++d4) {
      f4v w = w4[d4], q = q4[d4];
      a += w[0]*q[0] + w[1]*q[1] + w[2]*q[2] + w[3]*q[3];
    }
    qeff[(size_t)(b * H_ + h) * LOW_ + l] = f2bf(a);
  }
}

// score_r[b,s] = rope(qr_pre[b], 4095) . rope(kr[b,s], s)   (raw, unscaled)
__global__ __launch_bounds__(128) void rope_score_kernel(
    const float* __restrict__ kr_cache, const float* __restrict__ kr_new,
    const float* __restrict__ qr_pre, float* __restrict__ score_r)
{
  int b = blockIdx.y;
  int s = blockIdx.x * 128 + threadIdx.x;
  int t = threadIdx.x;
  __shared__ float invf[64];
  __shared__ float qr[128];
  if (t < 64) invf[t] = 1.0f / powf(10000.0f, (float)t * (1.0f / 64.0f));
  __syncthreads();
  if (t < 64) {
    float x1 = qr_pre[b * HD_ + t], x2 = qr_pre[b * HD_ + 64 + t];
    float sn, cs; sincosf(4095.0f * invf[t], &sn, &cs);
    qr[t]      = x1 * cs - x2 * sn;
    qr[64 + t] = x1 * sn + x2 * cs;
  }
  __syncthreads();
  const float* krp = (s == S_ - 1) ? (kr_new + b * HD_)
                                   : (kr_cache + ((size_t)b * SPREV + s) * HD_);
  float fs = (float)s;
  float dot = 0.f;
  #pragma unroll 4
  for (int j = 0; j < 64; ++j) {
    float x1 = krp[j], x2 = krp[64 + j];
    float sn, cs; sincosf(fs * invf[j], &sn, &cs);
    dot += qr[j] * (x1 * cs - x2 * sn) + qr[64 + j] * (x1 * sn + x2 * cs);
  }
  score_r[b * S_ + s] = dot;
}

// Flash-decode in latent space, one (b, 64-position chunk) per block.
// Phase A: S[16h][64s] = qeff(16x512) . ckv^T  via 16x16x32 bf16 MFMA.
// Phase B: chunk softmax (wave 0), P bf16.
// Phase C: acc[16h][512l] = P(16x64) . ckv(64x512) via MFMA, write partials.
__global__ __launch_bounds__(256) void attn_kernel(
    const float* __restrict__ ckv_cache, const float* __restrict__ ckv_new,
    const unsigned short* __restrict__ qeff, const float* __restrict__ score_r,
    unsigned short* __restrict__ acc_part, float* __restrict__ m_part,
    float* __restrict__ l_part)
{
  int chunk = blockIdx.x, b = blockIdx.y;
  int tid = threadIdx.x;
  int w = tid >> 6, lane = tid & 63;
  int kg = lane >> 4, l16 = lane & 15;
  __shared__ float S_lds[16 * 64];          // swizzled: idx = h*64 + (s ^ ((h&7)<<2))
  __shared__ unsigned short P_lds[16 * 64]; // swizzled: idx = h*64 + (s ^ ((h&7)<<3))

  { // ---- phase A ----
    int s_loc = w * 16 + l16;
    int s = chunk * CHK + s_loc;
    const float* crow = (s == S_ - 1) ? (ckv_new + b * LOW_)
                                      : (ckv_cache + ((size_t)b * SPREV + s) * LOW_);
    f4v acc = {0.f, 0.f, 0.f, 0.f};
    const s8v* qf = (const s8v*)(qeff + (size_t)(b * H_ + l16) * LOW_);
    #pragma unroll
    for (int kt = 0; kt < 16; ++kt) {
      s8v a = qf[kt * 4 + kg];
      const float* cp = crow + kt * 32 + kg * 8;
      f4v c0 = *(const f4v*)cp;
      f4v c1 = *(const f4v*)(cp + 4);
      s8v bv;
      bv[0]=(short)f2bf(c0[0]); bv[1]=(short)f2bf(c0[1]);
      bv[2]=(short)f2bf(c0[2]); bv[3]=(short)f2bf(c0[3]);
      bv[4]=(short)f2bf(c1[0]); bv[5]=(short)f2bf(c1[1]);
      bv[6]=(short)f2bf(c1[2]); bv[7]=(short)f2bf(c1[3]);
      acc = __builtin_amdgcn_mfma_f32_16x16x32_bf16(a, bv, acc, 0, 0, 0);
    }
    #pragma unroll
    for (int r = 0; r < 4; ++r) {
      int h = kg * 4 + r;
      S_lds[h * 64 + (s_loc ^ ((h & 7) << 2))] = acc[r];
    }
  }
  __syncthreads();

  if (w == 0) { // ---- phase B: lane = part*16 + h; part owns 16 s ----
    int h = l16, part = kg;
    float v[16];
    #pragma unroll
    for (int jj = 0; jj < 4; ++jj) {
      int sb = part * 16 + jj * 4;
      f4v sv = *(const f4v*)&S_lds[h * 64 + (sb ^ ((h & 7) << 2))];
      f4v rv = *(const f4v*)&score_r[b * S_ + chunk * CHK + sb];
      #pragma unroll
      for (int q = 0; q < 4; ++q) v[jj * 4 + q] = (sv[q] + rv[q]) * 0.0625f;
    }
    float m = v[0];
    #pragma unroll
    for (int j = 1; j < 16; ++j) m = fmaxf(m, v[j]);
    m = fmaxf(m, __shfl_xor(m, 16));
    m = fmaxf(m, __shfl_xor(m, 32));
    float lsum = 0.f;
    #pragma unroll
    for (int j = 0; j < 16; ++j) { v[j] = expf(v[j] - m); lsum += v[j]; }
    lsum += __shfl_xor(lsum, 16);
    lsum += __shfl_xor(lsum, 32);
    #pragma unroll
    for (int jj = 0; jj < 8; ++jj) {
      int sb = part * 16 + jj * 2;
      unsigned pk = (unsigned)f2bf(v[jj*2]) | ((unsigned)f2bf(v[jj*2+1]) << 16);
      *(unsigned*)&P_lds[h * 64 + (sb ^ ((h & 7) << 3))] = pk;
    }
    if (part == 0) {
      int idx = (b * NCH + chunk) * H_ + h;
      m_part[idx] = m;
      l_part[idx] = lsum;
    }
  }
  __syncthreads();

  { // ---- phase C: wave w owns l in [w*128, w*128+128) ----
    s8v pa[2];
    const float* rp[2][8];
    #pragma unroll
    for (int kt = 0; kt < 2; ++kt) {
      int so = kt * 32 + kg * 8;
      pa[kt] = *(const s8v*)&P_lds[l16 * 64 + (so ^ ((l16 & 7) << 3))];
      #pragma unroll
      for (int i = 0; i < 8; ++i) {
        int s = chunk * CHK + so + i;
        rp[kt][i] = (s == S_ - 1) ? (ckv_new + b * LOW_)
                                  : (ckv_cache + ((size_t)b * SPREV + s) * LOW_);
      }
    }
    f4v oa[8];
    #pragma unroll
    for (int nt = 0; nt < 8; ++nt) oa[nt] = {0.f, 0.f, 0.f, 0.f};
    #pragma unroll
    for (int nt = 0; nt < 8; ++nt) {
      int l = w * 128 + nt * 16 + l16;
      #pragma unroll
      for (int kt = 0; kt < 2; ++kt) {
        s8v bv;
        #pragma unroll
        for (int i = 0; i < 8; ++i) bv[i] = (short)f2bf(rp[kt][i][l]);
        oa[nt] = __builtin_amdgcn_mfma_f32_16x16x32_bf16(pa[kt], bv, oa[nt], 0, 0, 0);
      }
    }
    size_t base = (size_t)(b * NCH + chunk) * H_;
    #pragma unroll
    for (int nt = 0; nt < 8; ++nt) {
      int l = w * 128 + nt * 16 + l16;
      #pragma unroll
      for (int r = 0; r < 4; ++r) {
        int h = kg * 4 + r;
        acc_part[(base + h) * LOW_ + l] = f2bf(oa[nt][r]);
      }
    }
  }
}

// Combine per-chunk partials -> wl[b,h,l] = softmax-weighted latent / L
__global__ __launch_bounds__(256) void reduce_kernel(
    const float* __restrict__ m_part, const float* __restrict__ l_part,
    const unsigned short* __restrict__ acc_part, float* __restrict__ wl)
{
  int h = blockIdx.x, b = blockIdx.y, t = threadIdx.x;
  __shared__ float wls[NCH];
  __shared__ float Linv_s;
  if (t < 64) {
    float mc = m_part[(b * NCH + t) * H_ + h];
    float M = mc;
    #pragma unroll
    for (int d = 1; d < 64; d <<= 1) M = fmaxf(M, __shfl_xor(M, d));
    float wc = expf(mc - M);
    float L = l_part[(b * NCH + t) * H_ + h] * wc;
    #pragma unroll
    for (int d = 1; d < 64; d <<= 1) L += __shfl_xor(L, d);
    wls[t] = wc;
    if (t == 0) Linv_s = 1.0f / L;
  }
  __syncthreads();
  float inv = Linv_s;
  int l0 = t * 2;
  float a0 = 0.f, a1 = 0.f;
  const unsigned short* ap = acc_part + ((size_t)(b * NCH) * H_ + h) * LOW_ + l0;
  #pragma unroll 4
  for (int c = 0; c < NCH; ++c) {
    unsigned pk = *(const unsigned*)(ap + (size_t)c * H_ * LOW_);
    float wc = wls[c];
    a0 = fmaf(bf2f((unsigned short)(pk & 0xffffu)), wc, a0);
    a1 = fmaf(bf2f((unsigned short)(pk >> 16)), wc, a1);
  }
  wl[(b * H_ + h) * LOW_ + l0]     = a0 * inv;
  wl[(b * H_ + h) * LOW_ + l0 + 1] = a1 * inv;
}

// o_heads[b, h*128+d] += sum_{l in quarter} wl[b,h,l] * FU[l, E + h*128 + d]
__global__ __launch_bounds__(128) void proj_v_kernel(
    const float* __restrict__ wl, const float* __restrict__ FU,
    float* __restrict__ o_heads)
{
  int h = blockIdx.x, b = blockIdx.y, lq = blockIdx.z;
  int d = threadIdx.x;
  __shared__ float wsh[128];
  wsh[d] = wl[(b * H_ + h) * LOW_ + lq * 128 + d];
  __syncthreads();
  float a = 0.f;
  const float* fp = FU + (size_t)(lq * 128) * (2 * E_) + E_ + h * HD_ + d;
  #pragma unroll 4
  for (int l = 0; l < 128; ++l)
    a = fmaf(wsh[l], fp[(size_t)l * (2 * E_)], a);
  atomicAdd(&o_heads[(b * H_ + h) * HD_ + d], a);
}

extern "C" void kernel_launch(void* const* d_in, const int* in_sizes, int n_in,
                              void* d_out, int out_size, void* d_ws, size_t ws_size,
                              hipStream_t stream)
{
  const float* x    = (const float*)d_in[0];
  const float* ckvc = (const float*)d_in[1];
  const float* krc  = (const float*)d_in[2];
  const float* Wdq  = (const float*)d_in[3];
  const float* Wuq  = (const float*)d_in[4];
  const float* Wqr  = (const float*)d_in[5];
  const float* Wdkv = (const float*)d_in[6];
  const float* Wkr  = (const float*)d_in[7];
  const float* FU   = (const float*)d_in[8];
  const float* Wo   = (const float*)d_in[9];
  float* out = (float*)d_out;

  char* ws = (char*)d_ws;
  float* Cq             = (float*)(ws + 0);        // 65536 B
  float* Qc             = (float*)(ws + 65536);    // 65536 B
  float* qr_pre         = (float*)(ws + 131072);   // 4096 B
  float* ckvn           = (float*)(ws + 135168);   // 16384 B
  float* krn            = (float*)(ws + 151552);   // 4096 B   [prefix end 155648]
  unsigned short* qeff  = (unsigned short*)(ws + 155648);  // 131072 B
  float* score_r        = (float*)(ws + 286720);   // 131072 B
  float* m_part         = (float*)(ws + 417792);   // 32768 B
  float* l_part         = (float*)(ws + 450560);   // 32768 B
  unsigned short* accp  = (unsigned short*)(ws + 483328);  // 8388608 B
  float* o_heads        = (float*)(ws + 8871936);  // 65536 B
  float* wl             = (float*)(ws + 8937472);  // 262144 B  (total ~9.2 MB)

  hipMemsetAsync(ws, 0, 155648, stream);       // atomic targets: Cq,Qc,qr_pre,ckvn,krn
  hipMemsetAsync(o_heads, 0, 65536, stream);
  hipMemsetAsync(out, 0, 65536, stream);

  // Cq = x@Wdq ; ckv_new = x@Wdkv ; kr_new = x@Wkr
  matvec8<<<dim3(21, 32), 128, 0, stream>>>(x, E_, Wdq, E_, Cq,
                                            Wdkv, LOW_, ckvn, Wkr, HD_, krn);
  // Qc = Cq@Wuq ; qr_pre = Cq@Wqr
  matvec8<<<dim3(17, 32), 128, 0, stream>>>(Cq, E_, Wuq, E_, Qc,
                                            Wqr, HD_, qr_pre,
                                            (const float*)nullptr, 0, (float*)nullptr);
  qeff_kernel<<<dim3(16, 8), 128, 0, stream>>>(Qc, FU, qeff);
  rope_score_kernel<<<dim3(32, 8), 128, 0, stream>>>(krc, krn, qr_pre, score_r);
  attn_kernel<<<dim3(64, 8), 256, 0, stream>>>(ckvc, ckvn, qeff, score_r,
                                               accp, m_part, l_part);
  reduce_kernel<<<dim3(16, 8), 256, 0, stream>>>(m_part, l_part, accp, wl);
  proj_v_kernel<<<dim3(16, 8, 4), 128, 0, stream>>>(wl, FU, o_heads);
  // out = o_heads @ Wo
  matvec8<<<dim3(16, 32), 128, 0, stream>>>(o_heads, E_, Wo, E_, out,
                                            (const float*)nullptr, 0, (float*)nullptr,
                                            (const float*)nullptr, 0, (float*)nullptr);
}

// Round 3
// 114.844 us; speedup vs baseline: 1.0819x; 1.0819x over previous
//
#include <hip/hip_runtime.h>
#include <hip/hip_bf16.h>

#define B_ 8
#define SPREV 4095
#define S_ 4096
#define E_ 2048
#define H_ 16
#define HD_ 128
#define LOW_ 512
#define NCH 64      // attention s-chunks per batch
#define CHK 64      // positions per chunk
#define CKV_STRIDE 520  // bf16 elems per LDS row (1040 B, 16-B aligned, depads banks)

typedef short s8v __attribute__((ext_vector_type(8)));
typedef float f4v __attribute__((ext_vector_type(4)));

__device__ __forceinline__ short f2bf_s(float f) {
  return (short)__bfloat16_as_ushort(__float2bfloat16(f));
}
__device__ __forceinline__ float bf2f(unsigned short h) {
  union { unsigned u; float f; } v; v.u = ((unsigned)h) << 16;
  return v.f;
}

// Zero all accumulation targets in one launch: ws[0..38912) floats + out[0..16384)
__global__ __launch_bounds__(256) void zero_kernel(float* __restrict__ ws_pre,
                                                   float* __restrict__ out) {
  int i = blockIdx.x * 256 + threadIdx.x;
  if (i < 38912) ws_pre[i] = 0.f;
  else if (i < 38912 + 16384) out[i - 38912] = 0.f;
}

// out[b][n] += sum_k x[b][k] * W[k][n], k in [k0, k0+64). Up to 3 column
// segments (separate W/out), each N a multiple of 128. atomicAdd into out.
__global__ __launch_bounds__(128) void matvec8(
    const float* __restrict__ x, int K,
    const float* __restrict__ W0, int N0, float* __restrict__ o0,
    const float* __restrict__ W1, int N1, float* __restrict__ o1,
    const float* __restrict__ W2, int N2, float* __restrict__ o2)
{
  int cb = blockIdx.x;
  int nb0 = N0 >> 7, nb1 = N1 >> 7;
  const float* W; float* o; int N, colbase;
  if (cb < nb0)            { W = W0; o = o0; N = N0; colbase = cb << 7; }
  else if (cb < nb0 + nb1) { W = W1; o = o1; N = N1; colbase = (cb - nb0) << 7; }
  else                     { W = W2; o = o2; N = N2; colbase = (cb - nb0 - nb1) << 7; }
  int col = colbase + threadIdx.x;
  int k0 = blockIdx.y * 64;
  float acc[B_];
  #pragma unroll
  for (int b = 0; b < B_; ++b) acc[b] = 0.f;
  const float* Wp = W + (size_t)k0 * N + col;
  #pragma unroll 4
  for (int k = 0; k < 64; ++k) {
    float wv = Wp[(size_t)k * N];
    #pragma unroll
    for (int b = 0; b < B_; ++b)
      acc[b] = fmaf(x[b * K + k0 + k], wv, acc[b]);   // uniform -> s_load
  }
  #pragma unroll
  for (int b = 0; b < B_; ++b) atomicAdd(&o[b * N + col], acc[b]);
}

// Merged: blocks x<16 compute qeff[b,h,l]; blocks x>=16 compute rope scores.
__global__ __launch_bounds__(128) void qeff_rope_kernel(
    const float* __restrict__ Qc, const float* __restrict__ FU,
    unsigned short* __restrict__ qeff,
    const float* __restrict__ kr_cache, const float* __restrict__ kr_new,
    const float* __restrict__ qr_pre, float* __restrict__ score_r)
{
  int bx = blockIdx.x, b = blockIdx.y, t = threadIdx.x;
  if (bx < 16) {
    // qeff[b,h,l] = sum_d FU[l, h*128+d] * Qc[b, h*128+d]
    int h = bx;
    __shared__ float qs[HD_];
    qs[t] = Qc[b * E_ + h * HD_ + t];
    __syncthreads();
    const f4v* q4 = (const f4v*)qs;
    #pragma unroll
    for (int li = 0; li < 4; ++li) {
      int l = t + li * 128;
      const f4v* w4 = (const f4v*)(FU + (size_t)l * (2 * E_) + h * HD_);
      float a = 0.f;
      #pragma unroll 8
      for (int d4 = 0; d4 < 32; ++d4) {
        f4v w = w4[d4], q = q4[d4];
        a += w[0]*q[0] + w[1]*q[1] + w[2]*q[2] + w[3]*q[3];
      }
      qeff[(size_t)(b * H_ + h) * LOW_ + l] = (unsigned short)f2bf_s(a);
    }
  } else {
    // score_r[b,s] = rope(qr_pre[b], 4095) . rope(kr[b,s], s)
    int s = (bx - 16) * 128 + t;
    __shared__ float invf[64];
    __shared__ float qr[128];
    if (t < 64) invf[t] = 1.0f / powf(10000.0f, (float)t * (1.0f / 64.0f));
    __syncthreads();
    if (t < 64) {
      float x1 = qr_pre[b * HD_ + t], x2 = qr_pre[b * HD_ + 64 + t];
      float sn, cs; sincosf(4095.0f * invf[t], &sn, &cs);
      qr[t]      = x1 * cs - x2 * sn;
      qr[64 + t] = x1 * sn + x2 * cs;
    }
    __syncthreads();
    const float* krp = (s == S_ - 1) ? (kr_new + b * HD_)
                                     : (kr_cache + ((size_t)b * SPREV + s) * HD_);
    float fs = (float)s;
    float dot = 0.f;
    #pragma unroll 4
    for (int j = 0; j < 64; ++j) {
      float x1 = krp[j], x2 = krp[64 + j];
      float sn, cs; sincosf(fs * invf[j], &sn, &cs);
      dot += qr[j] * (x1 * cs - x2 * sn) + qr[64 + j] * (x1 * sn + x2 * cs);
    }
    score_r[b * S_ + s] = dot;
  }
}

// Flash-decode in latent space, one (b, 64-position chunk) per block.
// Phase A: S[16h][64s] = qeff(16x512) . ckv^T via MFMA; stage bf16 ckv in LDS.
// Phase B: chunk softmax (wave 0), P bf16.
// Phase C: acc[16h][512l] = P(16x64) . ckv(64x512) via MFMA (B-frags from LDS).
__global__ __launch_bounds__(256) void attn_kernel(
    const float* __restrict__ ckv_cache, const float* __restrict__ ckv_new,
    const unsigned short* __restrict__ qeff, const float* __restrict__ score_r,
    unsigned short* __restrict__ acc_part, float* __restrict__ m_part,
    float* __restrict__ l_part)
{
  int chunk = blockIdx.x, b = blockIdx.y;
  int tid = threadIdx.x;
  int w = tid >> 6, lane = tid & 63;
  int kg = lane >> 4, l16 = lane & 15;
  __shared__ float S_lds[16 * 64];               // swizzled: h*64 + (s ^ ((h&7)<<2))
  __shared__ unsigned short P_lds[16 * 64];      // swizzled: h*64 + (s ^ ((h&7)<<3))
  __shared__ unsigned short ckv_lds[64 * CKV_STRIDE];  // [s][l] bf16, padded stride

  { // ---- phase A ----
    int s_loc = w * 16 + l16;
    int s = chunk * CHK + s_loc;
    const float* crow = (s == S_ - 1) ? (ckv_new + b * LOW_)
                                      : (ckv_cache + ((size_t)b * SPREV + s) * LOW_);
    f4v acc = {0.f, 0.f, 0.f, 0.f};
    const s8v* qf = (const s8v*)(qeff + (size_t)(b * H_ + l16) * LOW_);
    #pragma unroll
    for (int kt = 0; kt < 16; ++kt) {
      s8v a = qf[kt * 4 + kg];
      const float* cp = crow + kt * 32 + kg * 8;
      f4v c0 = *(const f4v*)cp;
      f4v c1 = *(const f4v*)(cp + 4);
      s8v bv;
      bv[0]=f2bf_s(c0[0]); bv[1]=f2bf_s(c0[1]); bv[2]=f2bf_s(c0[2]); bv[3]=f2bf_s(c0[3]);
      bv[4]=f2bf_s(c1[0]); bv[5]=f2bf_s(c1[1]); bv[6]=f2bf_s(c1[2]); bv[7]=f2bf_s(c1[3]);
      *(s8v*)&ckv_lds[s_loc * CKV_STRIDE + kt * 32 + kg * 8] = bv;  // stage for phase C
      acc = __builtin_amdgcn_mfma_f32_16x16x32_bf16(a, bv, acc, 0, 0, 0);
    }
    #pragma unroll
    for (int r = 0; r < 4; ++r) {
      int h = kg * 4 + r;
      S_lds[h * 64 + (s_loc ^ ((h & 7) << 2))] = acc[r];
    }
  }
  __syncthreads();

  if (w == 0) { // ---- phase B: lane = part*16 + h; part owns 16 s ----
    int h = l16, part = kg;
    float v[16];
    #pragma unroll
    for (int jj = 0; jj < 4; ++jj) {
      int sb = part * 16 + jj * 4;
      f4v sv = *(const f4v*)&S_lds[h * 64 + (sb ^ ((h & 7) << 2))];
      f4v rv = *(const f4v*)&score_r[b * S_ + chunk * CHK + sb];
      #pragma unroll
      for (int q = 0; q < 4; ++q) v[jj * 4 + q] = (sv[q] + rv[q]) * 0.0625f;
    }
    float m = v[0];
    #pragma unroll
    for (int j = 1; j < 16; ++j) m = fmaxf(m, v[j]);
    m = fmaxf(m, __shfl_xor(m, 16));
    m = fmaxf(m, __shfl_xor(m, 32));
    float lsum = 0.f;
    #pragma unroll
    for (int j = 0; j < 16; ++j) { v[j] = expf(v[j] - m); lsum += v[j]; }
    lsum += __shfl_xor(lsum, 16);
    lsum += __shfl_xor(lsum, 32);
    #pragma unroll
    for (int jj = 0; jj < 8; ++jj) {
      int sb = part * 16 + jj * 2;
      unsigned pk = (unsigned)(unsigned short)f2bf_s(v[jj*2]) |
                    ((unsigned)(unsigned short)f2bf_s(v[jj*2+1]) << 16);
      *(unsigned*)&P_lds[h * 64 + (sb ^ ((h & 7) << 3))] = pk;
    }
    if (part == 0) {
      int idx = (b * NCH + chunk) * H_ + h;
      m_part[idx] = m;
      l_part[idx] = lsum;
    }
  }
  __syncthreads();

  { // ---- phase C: wave w owns l in [w*128, w*128+128) ----
    s8v pa[2];
    #pragma unroll
    for (int kt = 0; kt < 2; ++kt) {
      int so = kt * 32 + kg * 8;
      pa[kt] = *(const s8v*)&P_lds[l16 * 64 + (so ^ ((l16 & 7) << 3))];
    }
    f4v oa[8];
    #pragma unroll
    for (int nt = 0; nt < 8; ++nt) oa[nt] = {0.f, 0.f, 0.f, 0.f};
    #pragma unroll
    for (int nt = 0; nt < 8; ++nt) {
      int l = w * 128 + nt * 16 + l16;
      #pragma unroll
      for (int kt = 0; kt < 2; ++kt) {
        int so = kt * 32 + kg * 8;
        s8v bv;
        #pragma unroll
        for (int i = 0; i < 8; ++i)
          bv[i] = (short)ckv_lds[(so + i) * CKV_STRIDE + l];
        oa[nt] = __builtin_amdgcn_mfma_f32_16x16x32_bf16(pa[kt], bv, oa[nt], 0, 0, 0);
      }
    }
    size_t base = (size_t)(b * NCH + chunk) * H_;
    #pragma unroll
    for (int nt = 0; nt < 8; ++nt) {
      int l = w * 128 + nt * 16 + l16;
      #pragma unroll
      for (int r = 0; r < 4; ++r) {
        int h = kg * 4 + r;
        acc_part[(base + h) * LOW_ + l] = (unsigned short)f2bf_s(oa[nt][r]);
      }
    }
  }
}

// Fused: combine per-chunk partials into wl row (LDS), then project through
// FU's V half -> o_heads[b, h*128+d]. One block per (h, b); no atomics.
__global__ __launch_bounds__(256) void reduce_proj_kernel(
    const float* __restrict__ m_part, const float* __restrict__ l_part,
    const unsigned short* __restrict__ acc_part, const float* __restrict__ FU,
    float* __restrict__ o_heads)
{
  int h = blockIdx.x, b = blockIdx.y, t = threadIdx.x;
  __shared__ float wls[NCH];
  __shared__ float Linv_s;
  __shared__ float wl_sh[LOW_];
  __shared__ float part[256];
  if (t < 64) {
    float mc = m_part[(b * NCH + t) * H_ + h];
    float M = mc;
    #pragma unroll
    for (int d = 1; d < 64; d <<= 1) M = fmaxf(M, __shfl_xor(M, d));
    float wc = expf(mc - M);
    float L = l_part[(b * NCH + t) * H_ + h] * wc;
    #pragma unroll
    for (int d = 1; d < 64; d <<= 1) L += __shfl_xor(L, d);
    wls[t] = wc;
    if (t == 0) Linv_s = 1.0f / L;
  }
  __syncthreads();
  float inv = Linv_s;
  int l0 = t * 2;
  float a0 = 0.f, a1 = 0.f;
  const unsigned short* ap = acc_part + ((size_t)(b * NCH) * H_ + h) * LOW_ + l0;
  #pragma unroll 4
  for (int c = 0; c < NCH; ++c) {
    unsigned pk = *(const unsigned*)(ap + (size_t)c * H_ * LOW_);
    float wc = wls[c];
    a0 = fmaf(bf2f((unsigned short)(pk & 0xffffu)), wc, a0);
    a1 = fmaf(bf2f((unsigned short)(pk >> 16)), wc, a1);
  }
  wl_sh[l0]     = a0 * inv;
  wl_sh[l0 + 1] = a1 * inv;
  __syncthreads();
  // proj: o_heads[b, h*128+d] = sum_l wl_sh[l] * FU[l, E + h*128 + d]
  int half = t >> 7, d = t & 127;
  const float* fp = FU + (size_t)(half * 256) * (2 * E_) + E_ + h * HD_ + d;
  float a = 0.f;
  #pragma unroll 4
  for (int l = 0; l < 256; ++l)
    a = fmaf(wl_sh[half * 256 + l], fp[(size_t)l * (2 * E_)], a);
  part[t] = a;
  __syncthreads();
  if (t < 128)
    o_heads[(b * H_ + h) * HD_ + t] = part[t] + part[t + 128];
}

extern "C" void kernel_launch(void* const* d_in, const int* in_sizes, int n_in,
                              void* d_out, int out_size, void* d_ws, size_t ws_size,
                              hipStream_t stream)
{
  const float* x    = (const float*)d_in[0];
  const float* ckvc = (const float*)d_in[1];
  const float* krc  = (const float*)d_in[2];
  const float* Wdq  = (const float*)d_in[3];
  const float* Wuq  = (const float*)d_in[4];
  const float* Wqr  = (const float*)d_in[5];
  const float* Wdkv = (const float*)d_in[6];
  const float* Wkr  = (const float*)d_in[7];
  const float* FU   = (const float*)d_in[8];
  const float* Wo   = (const float*)d_in[9];
  float* out = (float*)d_out;

  char* ws = (char*)d_ws;
  float* Cq             = (float*)(ws + 0);        // 65536 B
  float* Qc             = (float*)(ws + 65536);    // 65536 B
  float* qr_pre         = (float*)(ws + 131072);   // 4096 B
  float* ckvn           = (float*)(ws + 135168);   // 16384 B
  float* krn            = (float*)(ws + 151552);   // 4096 B   [prefix end 155648]
  unsigned short* qeff  = (unsigned short*)(ws + 155648);  // 131072 B
  float* score_r        = (float*)(ws + 286720);   // 131072 B
  float* m_part         = (float*)(ws + 417792);   // 32768 B
  float* l_part         = (float*)(ws + 450560);   // 32768 B
  unsigned short* accp  = (unsigned short*)(ws + 483328);  // 8388608 B
  float* o_heads        = (float*)(ws + 8871936);  // 65536 B (total ~8.9 MB)

  // One zero pass for all atomic-accumulation targets (replaces 3 memset fills)
  zero_kernel<<<216, 256, 0, stream>>>((float*)ws, out);

  // Cq = x@Wdq ; ckv_new = x@Wdkv ; kr_new = x@Wkr
  matvec8<<<dim3(21, 32), 128, 0, stream>>>(x, E_, Wdq, E_, Cq,
                                            Wdkv, LOW_, ckvn, Wkr, HD_, krn);
  // Qc = Cq@Wuq ; qr_pre = Cq@Wqr
  matvec8<<<dim3(17, 32), 128, 0, stream>>>(Cq, E_, Wuq, E_, Qc,
                                            Wqr, HD_, qr_pre,
                                            (const float*)nullptr, 0, (float*)nullptr);
  qeff_rope_kernel<<<dim3(48, 8), 128, 0, stream>>>(Qc, FU, qeff,
                                                    krc, krn, qr_pre, score_r);
  attn_kernel<<<dim3(64, 8), 256, 0, stream>>>(ckvc, ckvn, qeff, score_r,
                                               accp, m_part, l_part);
  reduce_proj_kernel<<<dim3(16, 8), 256, 0, stream>>>(m_part, l_part, accp,
                                                      FU, o_heads);
  // out = o_heads @ Wo
  matvec8<<<dim3(16, 32), 128, 0, stream>>>(o_heads, E_, Wo, E_, out,
                                            (const float*)nullptr, 0, (float*)nullptr,
                                            (const float*)nullptr, 0, (float*)nullptr);
}

// Round 4
// 106.948 us; speedup vs baseline: 1.1617x; 1.0738x over previous
//
#include <hip/hip_runtime.h>
#include <hip/hip_bf16.h>

#define B_ 8
#define SPREV 4095
#define S_ 4096
#define E_ 2048
#define H_ 16
#define HD_ 128
#define LOW_ 512
#define NCH 64      // attention s-chunks per batch
#define CHK 64      // positions per chunk
#define CKV_STRIDE 520  // bf16 elems per LDS row (1040 B, 16-B aligned, depads banks)

typedef short s8v __attribute__((ext_vector_type(8)));
typedef float f4v __attribute__((ext_vector_type(4)));

__device__ __forceinline__ short f2bf_s(float f) {
  return (short)__bfloat16_as_ushort(__float2bfloat16(f));
}
__device__ __forceinline__ float bf2f(unsigned short h) {
  union { unsigned u; float f; } v; v.u = ((unsigned)h) << 16;
  return v.f;
}

// Zero all accumulation targets + build rope cos/sin table tab2[j][s].
// grid 1024 x 256 -> i in [0, 262144)
__global__ __launch_bounds__(256) void init_kernel(float* __restrict__ ws_pre,
                                                   float* __restrict__ out,
                                                   float2* __restrict__ tab2) {
  int i = blockIdx.x * 256 + threadIdx.x;
  if (i < 120832) ws_pre[i] = 0.f;          // Cq,Qc,qr_pre,ckvn,krn,wl,o_heads
  else if (i < 137216) out[i - 120832] = 0.f;
  int j = i >> 12, s = i & 4095;
  float invf = powf(10000.0f, -(float)j * (1.0f / 64.0f));
  float sn, cs; sincosf((float)s * invf, &sn, &cs);
  tab2[i] = make_float2(cs, sn);
}

// out[b][n] += sum_k x[b][k] * W[k][n], k in [k0, k0+64). Up to 3 column
// segments (separate W/out), each N a multiple of 128. atomicAdd into out.
__global__ __launch_bounds__(128) void matvec8(
    const float* __restrict__ x, int K,
    const float* __restrict__ W0, int N0, float* __restrict__ o0,
    const float* __restrict__ W1, int N1, float* __restrict__ o1,
    const float* __restrict__ W2, int N2, float* __restrict__ o2)
{
  int cb = blockIdx.x;
  int nb0 = N0 >> 7, nb1 = N1 >> 7;
  const float* W; float* o; int N, colbase;
  if (cb < nb0)            { W = W0; o = o0; N = N0; colbase = cb << 7; }
  else if (cb < nb0 + nb1) { W = W1; o = o1; N = N1; colbase = (cb - nb0) << 7; }
  else                     { W = W2; o = o2; N = N2; colbase = (cb - nb0 - nb1) << 7; }
  int col = colbase + threadIdx.x;
  int k0 = blockIdx.y * 64;
  float acc[B_];
  #pragma unroll
  for (int b = 0; b < B_; ++b) acc[b] = 0.f;
  const float* Wp = W + (size_t)k0 * N + col;
  #pragma unroll 4
  for (int k = 0; k < 64; ++k) {
    float wv = Wp[(size_t)k * N];
    #pragma unroll
    for (int b = 0; b < B_; ++b)
      acc[b] = fmaf(x[b * K + k0 + k], wv, acc[b]);   // uniform -> s_load
  }
  #pragma unroll
  for (int b = 0; b < B_; ++b) atomicAdd(&o[b * N + col], acc[b]);
}

// Merged: blocks x<16 compute qeff[b,h,l]; blocks x>=16 compute rope scores
// (table-driven, no transcendentals in the hot loop).
__global__ __launch_bounds__(256) void qeff_rope_kernel(
    const float* __restrict__ Qc, const float* __restrict__ FU,
    unsigned short* __restrict__ qeff,
    const float* __restrict__ kr_cache, const float* __restrict__ kr_new,
    const float* __restrict__ qr_pre, const float2* __restrict__ tab2,
    float* __restrict__ score_r)
{
  int bx = blockIdx.x, b = blockIdx.y, t = threadIdx.x;
  if (bx < 16) {
    // qeff[b,h,l] = sum_d FU[l, h*128+d] * Qc[b, h*128+d]
    int h = bx;
    __shared__ float qs[HD_];
    if (t < 128) qs[t] = Qc[b * E_ + h * HD_ + t];
    __syncthreads();
    const f4v* q4 = (const f4v*)qs;
    #pragma unroll
    for (int li = 0; li < 2; ++li) {
      int l = t + li * 256;
      const f4v* w4 = (const f4v*)(FU + (size_t)l * (2 * E_) + h * HD_);
      float a = 0.f;
      #pragma unroll 8
      for (int d4 = 0; d4 < 32; ++d4) {
        f4v w = w4[d4], q = q4[d4];
        a += w[0]*q[0] + w[1]*q[1] + w[2]*q[2] + w[3]*q[3];
      }
      qeff[(size_t)(b * H_ + h) * LOW_ + l] = (unsigned short)f2bf_s(a);
    }
  } else {
    // score_r[b,s] = rope(qr_pre[b], 4095) . rope(kr[b,s], s)
    int s = (bx - 16) * 256 + t;
    __shared__ float qr[128];
    if (t < 64) {
      float invf = powf(10000.0f, -(float)t * (1.0f / 64.0f));
      float x1 = qr_pre[b * HD_ + t], x2 = qr_pre[b * HD_ + 64 + t];
      float sn, cs; sincosf(4095.0f * invf, &sn, &cs);
      qr[t]      = x1 * cs - x2 * sn;
      qr[64 + t] = x1 * sn + x2 * cs;
    }
    __syncthreads();
    const float* krp = (s == S_ - 1) ? (kr_new + b * HD_)
                                     : (kr_cache + ((size_t)b * SPREV + s) * HD_);
    float dot = 0.f;
    #pragma unroll 4
    for (int j = 0; j < 64; ++j) {
      float2 cs2 = tab2[j * 4096 + s];             // coalesced across lanes
      float x1 = krp[j], x2 = krp[64 + j];
      dot += qr[j] * (x1 * cs2.x - x2 * cs2.y) + qr[64 + j] * (x1 * cs2.y + x2 * cs2.x);
    }
    score_r[b * S_ + s] = dot;
  }
}

// Flash-decode in latent space, one (b, 64-position chunk) per block.
// Phase A: S[16h][64s] = qeff(16x512) . ckv^T via MFMA; stage bf16 ckv in LDS.
// Phase B: chunk softmax (wave 0), P bf16.
// Phase C: acc[16h][512l] = P(16x64) . ckv(64x512) via MFMA (B-frags from LDS).
__global__ __launch_bounds__(256) void attn_kernel(
    const float* __restrict__ ckv_cache, const float* __restrict__ ckv_new,
    const unsigned short* __restrict__ qeff, const float* __restrict__ score_r,
    unsigned short* __restrict__ acc_part, float* __restrict__ m_part,
    float* __restrict__ l_part)
{
  int chunk = blockIdx.x, b = blockIdx.y;
  int tid = threadIdx.x;
  int w = tid >> 6, lane = tid & 63;
  int kg = lane >> 4, l16 = lane & 15;
  __shared__ float S_lds[16 * 64];               // swizzled: h*64 + (s ^ ((h&7)<<2))
  __shared__ unsigned short P_lds[16 * 64];      // swizzled: h*64 + (s ^ ((h&7)<<3))
  __shared__ unsigned short ckv_lds[64 * CKV_STRIDE];  // [s][l] bf16, padded stride

  { // ---- phase A ----
    int s_loc = w * 16 + l16;
    int s = chunk * CHK + s_loc;
    const float* crow = (s == S_ - 1) ? (ckv_new + b * LOW_)
                                      : (ckv_cache + ((size_t)b * SPREV + s) * LOW_);
    f4v acc = {0.f, 0.f, 0.f, 0.f};
    const s8v* qf = (const s8v*)(qeff + (size_t)(b * H_ + l16) * LOW_);
    #pragma unroll
    for (int kt = 0; kt < 16; ++kt) {
      s8v a = qf[kt * 4 + kg];
      const float* cp = crow + kt * 32 + kg * 8;
      f4v c0 = *(const f4v*)cp;
      f4v c1 = *(const f4v*)(cp + 4);
      s8v bv;
      bv[0]=f2bf_s(c0[0]); bv[1]=f2bf_s(c0[1]); bv[2]=f2bf_s(c0[2]); bv[3]=f2bf_s(c0[3]);
      bv[4]=f2bf_s(c1[0]); bv[5]=f2bf_s(c1[1]); bv[6]=f2bf_s(c1[2]); bv[7]=f2bf_s(c1[3]);
      *(s8v*)&ckv_lds[s_loc * CKV_STRIDE + kt * 32 + kg * 8] = bv;  // stage for phase C
      acc = __builtin_amdgcn_mfma_f32_16x16x32_bf16(a, bv, acc, 0, 0, 0);
    }
    #pragma unroll
    for (int r = 0; r < 4; ++r) {
      int h = kg * 4 + r;
      S_lds[h * 64 + (s_loc ^ ((h & 7) << 2))] = acc[r];
    }
  }
  __syncthreads();

  if (w == 0) { // ---- phase B: lane = part*16 + h; part owns 16 s ----
    int h = l16, part = kg;
    float v[16];
    #pragma unroll
    for (int jj = 0; jj < 4; ++jj) {
      int sb = part * 16 + jj * 4;
      f4v sv = *(const f4v*)&S_lds[h * 64 + (sb ^ ((h & 7) << 2))];
      f4v rv = *(const f4v*)&score_r[b * S_ + chunk * CHK + sb];
      #pragma unroll
      for (int q = 0; q < 4; ++q) v[jj * 4 + q] = (sv[q] + rv[q]) * 0.0625f;
    }
    float m = v[0];
    #pragma unroll
    for (int j = 1; j < 16; ++j) m = fmaxf(m, v[j]);
    m = fmaxf(m, __shfl_xor(m, 16));
    m = fmaxf(m, __shfl_xor(m, 32));
    float lsum = 0.f;
    #pragma unroll
    for (int j = 0; j < 16; ++j) { v[j] = expf(v[j] - m); lsum += v[j]; }
    lsum += __shfl_xor(lsum, 16);
    lsum += __shfl_xor(lsum, 32);
    #pragma unroll
    for (int jj = 0; jj < 8; ++jj) {
      int sb = part * 16 + jj * 2;
      unsigned pk = (unsigned)(unsigned short)f2bf_s(v[jj*2]) |
                    ((unsigned)(unsigned short)f2bf_s(v[jj*2+1]) << 16);
      *(unsigned*)&P_lds[h * 64 + (sb ^ ((h & 7) << 3))] = pk;
    }
    if (part == 0) {
      int idx = (b * NCH + chunk) * H_ + h;
      m_part[idx] = m;
      l_part[idx] = lsum;
    }
  }
  __syncthreads();

  { // ---- phase C: wave w owns l in [w*128, w*128+128) ----
    s8v pa[2];
    #pragma unroll
    for (int kt = 0; kt < 2; ++kt) {
      int so = kt * 32 + kg * 8;
      pa[kt] = *(const s8v*)&P_lds[l16 * 64 + (so ^ ((l16 & 7) << 3))];
    }
    f4v oa[8];
    #pragma unroll
    for (int nt = 0; nt < 8; ++nt) oa[nt] = {0.f, 0.f, 0.f, 0.f};
    #pragma unroll
    for (int nt = 0; nt < 8; ++nt) {
      int l = w * 128 + nt * 16 + l16;
      #pragma unroll
      for (int kt = 0; kt < 2; ++kt) {
        int so = kt * 32 + kg * 8;
        s8v bv;
        #pragma unroll
        for (int i = 0; i < 8; ++i)
          bv[i] = (short)ckv_lds[(so + i) * CKV_STRIDE + l];
        oa[nt] = __builtin_amdgcn_mfma_f32_16x16x32_bf16(pa[kt], bv, oa[nt], 0, 0, 0);
      }
    }
    size_t base = (size_t)(b * NCH + chunk) * H_;
    #pragma unroll
    for (int nt = 0; nt < 8; ++nt) {
      int l = w * 128 + nt * 16 + l16;
      #pragma unroll
      for (int r = 0; r < 4; ++r) {
        int h = kg * 4 + r;
        acc_part[(base + h) * LOW_ + l] = (unsigned short)f2bf_s(oa[nt][r]);
      }
    }
  }
}

// Combine per-chunk partials: each block = (h, b, cz) handles 8 chunks x 512 l,
// atomicAdd f32 partial into wl. grid (16,8,8) x 128 thr.
__global__ __launch_bounds__(128) void reduce_kernel(
    const float* __restrict__ m_part, const float* __restrict__ l_part,
    const unsigned short* __restrict__ acc_part, float* __restrict__ wl)
{
  int h = blockIdx.x, b = blockIdx.y, cz = blockIdx.z, t = threadIdx.x;
  __shared__ float wli[8];
  if (t < 64) {
    float mc = m_part[(b * NCH + t) * H_ + h];
    float M = mc;
    #pragma unroll
    for (int d = 1; d < 64; d <<= 1) M = fmaxf(M, __shfl_xor(M, d));
    float wc = expf(mc - M);
    float L = l_part[(b * NCH + t) * H_ + h] * wc;
    #pragma unroll
    for (int d = 1; d < 64; d <<= 1) L += __shfl_xor(L, d);
    int rel = t - cz * 8;
    if (rel >= 0 && rel < 8) wli[rel] = wc / L;
  }
  __syncthreads();
  int l0 = t * 4;
  float a0 = 0.f, a1 = 0.f, a2 = 0.f, a3 = 0.f;
  const unsigned short* ap =
      acc_part + ((size_t)(b * NCH + cz * 8) * H_ + h) * LOW_ + l0;
  #pragma unroll
  for (int c = 0; c < 8; ++c) {
    uint2 pk = *(const uint2*)(ap + (size_t)c * H_ * LOW_);
    float wc = wli[c];
    a0 = fmaf(bf2f((unsigned short)(pk.x & 0xffffu)), wc, a0);
    a1 = fmaf(bf2f((unsigned short)(pk.x >> 16)),     wc, a1);
    a2 = fmaf(bf2f((unsigned short)(pk.y & 0xffffu)), wc, a2);
    a3 = fmaf(bf2f((unsigned short)(pk.y >> 16)),     wc, a3);
  }
  float* wp = wl + (size_t)(b * H_ + h) * LOW_ + l0;
  atomicAdd(wp, a0); atomicAdd(wp + 1, a1);
  atomicAdd(wp + 2, a2); atomicAdd(wp + 3, a3);
}

// Project weighted latent through FU's V half. Each block = (h, b, lz):
// 64-l slice, full 128 d; atomicAdd into o_heads. grid (16,8,8) x 128 thr.
__global__ __launch_bounds__(128) void proj_kernel(
    const float* __restrict__ wl, const float* __restrict__ FU,
    float* __restrict__ o_heads)
{
  int h = blockIdx.x, b = blockIdx.y, lz = blockIdx.z, d = threadIdx.x;
  __shared__ float wsh[64];
  if (d < 64) wsh[d] = wl[(b * H_ + h) * LOW_ + lz * 64 + d];
  __syncthreads();
  float a = 0.f;
  const float* fp = FU + (size_t)(lz * 64) * (2 * E_) + E_ + h * HD_ + d;
  #pragma unroll 4
  for (int l = 0; l < 64; ++l)
    a = fmaf(wsh[l], fp[(size_t)l * (2 * E_)], a);
  atomicAdd(&o_heads[(b * H_ + h) * HD_ + d], a);
}

extern "C" void kernel_launch(void* const* d_in, const int* in_sizes, int n_in,
                              void* d_out, int out_size, void* d_ws, size_t ws_size,
                              hipStream_t stream)
{
  const float* x    = (const float*)d_in[0];
  const float* ckvc = (const float*)d_in[1];
  const float* krc  = (const float*)d_in[2];
  const float* Wdq  = (const float*)d_in[3];
  const float* Wuq  = (const float*)d_in[4];
  const float* Wqr  = (const float*)d_in[5];
  const float* Wdkv = (const float*)d_in[6];
  const float* Wkr  = (const float*)d_in[7];
  const float* FU   = (const float*)d_in[8];
  const float* Wo   = (const float*)d_in[9];
  float* out = (float*)d_out;

  char* ws = (char*)d_ws;
  // zeroed prefix (120832 floats):
  float* Cq             = (float*)(ws + 0);        // 65536 B
  float* Qc             = (float*)(ws + 65536);    // 65536 B
  float* qr_pre         = (float*)(ws + 131072);   // 4096 B
  float* ckvn           = (float*)(ws + 135168);   // 16384 B
  float* krn            = (float*)(ws + 151552);   // 4096 B
  float* wl             = (float*)(ws + 155648);   // 262144 B
  float* o_heads        = (float*)(ws + 417792);   // 65536 B  [prefix end 483328]
  unsigned short* qeff  = (unsigned short*)(ws + 483328);  // 131072 B
  float* score_r        = (float*)(ws + 614400);   // 131072 B
  float* m_part         = (float*)(ws + 745472);   // 32768 B
  float* l_part         = (float*)(ws + 778240);   // 32768 B
  unsigned short* accp  = (unsigned short*)(ws + 811008);  // 8388608 B
  float2* tab2          = (float2*)(ws + 9199616); // 2097152 B (total ~11.3 MB)

  // Zero all atomic targets + build rope table (replaces memsets + sincos loop)
  init_kernel<<<1024, 256, 0, stream>>>((float*)ws, out, tab2);

  // Cq = x@Wdq ; ckv_new = x@Wdkv ; kr_new = x@Wkr
  matvec8<<<dim3(21, 32), 128, 0, stream>>>(x, E_, Wdq, E_, Cq,
                                            Wdkv, LOW_, ckvn, Wkr, HD_, krn);
  // Qc = Cq@Wuq ; qr_pre = Cq@Wqr
  matvec8<<<dim3(17, 32), 128, 0, stream>>>(Cq, E_, Wuq, E_, Qc,
                                            Wqr, HD_, qr_pre,
                                            (const float*)nullptr, 0, (float*)nullptr);
  qeff_rope_kernel<<<dim3(32, 8), 256, 0, stream>>>(Qc, FU, qeff,
                                                    krc, krn, qr_pre, tab2, score_r);
  attn_kernel<<<dim3(64, 8), 256, 0, stream>>>(ckvc, ckvn, qeff, score_r,
                                               accp, m_part, l_part);
  reduce_kernel<<<dim3(16, 8, 8), 128, 0, stream>>>(m_part, l_part, accp, wl);
  proj_kernel<<<dim3(16, 8, 8), 128, 0, stream>>>(wl, FU, o_heads);
  // out = o_heads @ Wo
  matvec8<<<dim3(16, 32), 128, 0, stream>>>(o_heads, E_, Wo, E_, out,
                                            (const float*)nullptr, 0, (float*)nullptr,
                                            (const float*)nullptr, 0, (float*)nullptr);
}

// Round 5
// 96.763 us; speedup vs baseline: 1.2840x; 1.1053x over previous
//
#include <hip/hip_runtime.h>
#include <hip/hip_bf16.h>

#define B_ 8
#define SPREV 4095
#define S_ 4096
#define E_ 2048
#define H_ 16
#define HD_ 128
#define LOW_ 512
#define NCH 64      // attention s-chunks per batch
#define CHK 64      // positions per chunk

typedef short s8v __attribute__((ext_vector_type(8)));
typedef float f4v __attribute__((ext_vector_type(4)));

__device__ __forceinline__ short f2bf_s(float f) {
  return (short)__bfloat16_as_ushort(__float2bfloat16(f));
}
__device__ __forceinline__ float bf2f(unsigned short h) {
  union { unsigned u; float f; } v; v.u = ((unsigned)h) << 16;
  return v.f;
}

// Zero all accumulation targets + build rope cos/sin table tab2[s][j] (float2).
// grid 1024 x 256 -> i in [0, 262144)
__global__ __launch_bounds__(256) void init_kernel(float* __restrict__ ws_pre,
                                                   float* __restrict__ out,
                                                   float2* __restrict__ tab2) {
  int i = blockIdx.x * 256 + threadIdx.x;
  if (i < 120832) ws_pre[i] = 0.f;          // Cq,Qc,qr_pre,ckvn,krn,wl,o_heads
  else if (i < 137216) out[i - 120832] = 0.f;
  int s = i >> 6, j = i & 63;               // [s][j] layout: rope loads coalesce
  float invf = powf(10000.0f, -(float)j * (1.0f / 64.0f));
  float sn, cs; sincosf((float)s * invf, &sn, &cs);
  tab2[i] = make_float2(cs, sn);
}

// out[b][n] += sum_k x[b][k] * W[k][n], k in [k0, k0+32). Up to 3 column
// segments (separate W/out), each N a multiple of 128. atomicAdd into out.
__global__ __launch_bounds__(128) void matvec8(
    const float* __restrict__ x, int K,
    const float* __restrict__ W0, int N0, float* __restrict__ o0,
    const float* __restrict__ W1, int N1, float* __restrict__ o1,
    const float* __restrict__ W2, int N2, float* __restrict__ o2)
{
  int cb = blockIdx.x;
  int nb0 = N0 >> 7, nb1 = N1 >> 7;
  const float* W; float* o; int N, colbase;
  if (cb < nb0)            { W = W0; o = o0; N = N0; colbase = cb << 7; }
  else if (cb < nb0 + nb1) { W = W1; o = o1; N = N1; colbase = (cb - nb0) << 7; }
  else                     { W = W2; o = o2; N = N2; colbase = (cb - nb0 - nb1) << 7; }
  int col = colbase + threadIdx.x;
  int k0 = blockIdx.y * 32;
  float acc[B_];
  #pragma unroll
  for (int b = 0; b < B_; ++b) acc[b] = 0.f;
  const float* Wp = W + (size_t)k0 * N + col;
  #pragma unroll 8
  for (int k = 0; k < 32; ++k) {
    float wv = Wp[(size_t)k * N];
    #pragma unroll
    for (int b = 0; b < B_; ++b)
      acc[b] = fmaf(x[b * K + k0 + k], wv, acc[b]);   // uniform -> s_load
  }
  #pragma unroll
  for (int b = 0; b < B_; ++b) atomicAdd(&o[b * N + col], acc[b]);
}

// Merged, 16-lanes-per-row mapping (coalesced 32B/lane reads + shfl reduce):
// blocks x<16: qeff[b,h,l] for h=bx; blocks x>=16: rope scores, 256 s each.
__global__ __launch_bounds__(256) void qeff_rope_kernel(
    const float* __restrict__ Qc, const float* __restrict__ FU,
    unsigned short* __restrict__ qeff,
    const float* __restrict__ kr_cache, const float* __restrict__ kr_new,
    const float* __restrict__ qr_pre, const float2* __restrict__ tab2,
    float* __restrict__ score_r)
{
  int bx = blockIdx.x, b = blockIdx.y, t = threadIdx.x;
  int g = t >> 4, li = t & 15;               // 16 groups x 16 lanes
  if (bx < 16) {
    // qeff[b,h,l] = sum_d FU[l, h*128+d] * Qc[b, h*128+d]
    int h = bx;
    __shared__ float qs[HD_];
    if (t < 128) qs[t] = Qc[b * E_ + h * HD_ + t];
    __syncthreads();
    f4v q0 = *(const f4v*)&qs[li * 8];
    f4v q1 = *(const f4v*)&qs[li * 8 + 4];
    #pragma unroll 4
    for (int p = 0; p < 32; ++p) {
      int l = p * 16 + g;
      const f4v* w4 = (const f4v*)(FU + (size_t)l * (2 * E_) + h * HD_ + li * 8);
      f4v w0 = w4[0], w1 = w4[1];
      float a = w0[0]*q0[0] + w0[1]*q0[1] + w0[2]*q0[2] + w0[3]*q0[3]
              + w1[0]*q1[0] + w1[1]*q1[1] + w1[2]*q1[2] + w1[3]*q1[3];
      a += __shfl_xor(a, 1); a += __shfl_xor(a, 2);
      a += __shfl_xor(a, 4); a += __shfl_xor(a, 8);
      if (li == 0) qeff[(size_t)(b * H_ + h) * LOW_ + l] = (unsigned short)f2bf_s(a);
    }
  } else {
    // score_r[b,s] = rope(qr_pre[b], 4095) . rope(kr[b,s], s)
    int s_base = (bx - 16) * 256;
    __shared__ float qr[128];
    if (t < 64) {
      float invf = powf(10000.0f, -(float)t * (1.0f / 64.0f));
      float x1 = qr_pre[b * HD_ + t], x2 = qr_pre[b * HD_ + 64 + t];
      float sn, cs; sincosf(4095.0f * invf, &sn, &cs);
      qr[t]      = x1 * cs - x2 * sn;
      qr[64 + t] = x1 * sn + x2 * cs;
    }
    __syncthreads();
    f4v qa = *(const f4v*)&qr[li * 4];
    f4v qb = *(const f4v*)&qr[64 + li * 4];
    #pragma unroll 2
    for (int p = 0; p < 16; ++p) {
      int s = s_base + p * 16 + g;
      const float* krp = (s == S_ - 1) ? (kr_new + b * HD_)
                                       : (kr_cache + ((size_t)b * SPREV + s) * HD_);
      f4v x1 = *(const f4v*)&krp[li * 4];
      f4v x2 = *(const f4v*)&krp[64 + li * 4];
      const float2* tp = &tab2[(size_t)s * 64 + li * 4];
      float dot = 0.f;
      #pragma unroll
      for (int q = 0; q < 4; ++q) {
        float2 cs2 = tp[q];
        dot += qa[q] * (x1[q] * cs2.x - x2[q] * cs2.y)
             + qb[q] * (x1[q] * cs2.y + x2[q] * cs2.x);
      }
      dot += __shfl_xor(dot, 1); dot += __shfl_xor(dot, 2);
      dot += __shfl_xor(dot, 4); dot += __shfl_xor(dot, 8);
      if (li == 0) score_r[b * S_ + s] = dot;
    }
  }
}

// Flash-decode in latent space, one (b, 64-position chunk) per block.
// Phase A: S[16h][64s] = qeff(16x512) . ckv^T via MFMA (global f4v loads).
// Phase B: chunk softmax (wave 0), P bf16.
// Phase C: acc[16h][512l] = P(16x64) . ckv(64x512) via MFMA, ckv re-read from
// global (L2-resident after phase A); small LDS -> high occupancy.
__global__ __launch_bounds__(256) void attn_kernel(
    const float* __restrict__ ckv_cache, const float* __restrict__ ckv_new,
    const unsigned short* __restrict__ qeff, const float* __restrict__ score_r,
    unsigned short* __restrict__ acc_part, float* __restrict__ m_part,
    float* __restrict__ l_part)
{
  int chunk = blockIdx.x, b = blockIdx.y;
  int tid = threadIdx.x;
  int w = tid >> 6, lane = tid & 63;
  int kg = lane >> 4, l16 = lane & 15;
  __shared__ float S_lds[16 * 64];          // swizzled: h*64 + (s ^ ((h&7)<<2))
  __shared__ unsigned short P_lds[16 * 64]; // swizzled: h*64 + (s ^ ((h&7)<<3))

  { // ---- phase A ----
    int s_loc = w * 16 + l16;
    int s = chunk * CHK + s_loc;
    const float* crow = (s == S_ - 1) ? (ckv_new + b * LOW_)
                                      : (ckv_cache + ((size_t)b * SPREV + s) * LOW_);
    f4v acc = {0.f, 0.f, 0.f, 0.f};
    const s8v* qf = (const s8v*)(qeff + (size_t)(b * H_ + l16) * LOW_);
    #pragma unroll
    for (int kt = 0; kt < 16; ++kt) {
      s8v a = qf[kt * 4 + kg];
      const float* cp = crow + kt * 32 + kg * 8;
      f4v c0 = *(const f4v*)cp;
      f4v c1 = *(const f4v*)(cp + 4);
      s8v bv;
      bv[0]=f2bf_s(c0[0]); bv[1]=f2bf_s(c0[1]); bv[2]=f2bf_s(c0[2]); bv[3]=f2bf_s(c0[3]);
      bv[4]=f2bf_s(c1[0]); bv[5]=f2bf_s(c1[1]); bv[6]=f2bf_s(c1[2]); bv[7]=f2bf_s(c1[3]);
      acc = __builtin_amdgcn_mfma_f32_16x16x32_bf16(a, bv, acc, 0, 0, 0);
    }
    #pragma unroll
    for (int r = 0; r < 4; ++r) {
      int h = kg * 4 + r;
      S_lds[h * 64 + (s_loc ^ ((h & 7) << 2))] = acc[r];
    }
  }
  __syncthreads();

  if (w == 0) { // ---- phase B: lane = part*16 + h; part owns 16 s ----
    int h = l16, part = kg;
    float v[16];
    #pragma unroll
    for (int jj = 0; jj < 4; ++jj) {
      int sb = part * 16 + jj * 4;
      f4v sv = *(const f4v*)&S_lds[h * 64 + (sb ^ ((h & 7) << 2))];
      f4v rv = *(const f4v*)&score_r[b * S_ + chunk * CHK + sb];
      #pragma unroll
      for (int q = 0; q < 4; ++q) v[jj * 4 + q] = (sv[q] + rv[q]) * 0.0625f;
    }
    float m = v[0];
    #pragma unroll
    for (int j = 1; j < 16; ++j) m = fmaxf(m, v[j]);
    m = fmaxf(m, __shfl_xor(m, 16));
    m = fmaxf(m, __shfl_xor(m, 32));
    float lsum = 0.f;
    #pragma unroll
    for (int j = 0; j < 16; ++j) { v[j] = expf(v[j] - m); lsum += v[j]; }
    lsum += __shfl_xor(lsum, 16);
    lsum += __shfl_xor(lsum, 32);
    #pragma unroll
    for (int jj = 0; jj < 8; ++jj) {
      int sb = part * 16 + jj * 2;
      unsigned pk = (unsigned)(unsigned short)f2bf_s(v[jj*2]) |
                    ((unsigned)(unsigned short)f2bf_s(v[jj*2+1]) << 16);
      *(unsigned*)&P_lds[h * 64 + (sb ^ ((h & 7) << 3))] = pk;
    }
    if (part == 0) {
      int idx = (b * NCH + chunk) * H_ + h;
      m_part[idx] = m;
      l_part[idx] = lsum;
    }
  }
  __syncthreads();

  { // ---- phase C: wave w owns l in [w*128, w*128+128) ----
    s8v pa[2];
    const float* rp[2][8];
    #pragma unroll
    for (int kt = 0; kt < 2; ++kt) {
      int so = kt * 32 + kg * 8;
      pa[kt] = *(const s8v*)&P_lds[l16 * 64 + (so ^ ((l16 & 7) << 3))];
      #pragma unroll
      for (int i = 0; i < 8; ++i) {
        int s = chunk * CHK + so + i;
        rp[kt][i] = (s == S_ - 1) ? (ckv_new + b * LOW_)
                                  : (ckv_cache + ((size_t)b * SPREV + s) * LOW_);
      }
    }
    f4v oa[8];
    #pragma unroll
    for (int nt = 0; nt < 8; ++nt) oa[nt] = {0.f, 0.f, 0.f, 0.f};
    #pragma unroll
    for (int nt = 0; nt < 8; ++nt) {
      int l = w * 128 + nt * 16 + l16;
      #pragma unroll
      for (int kt = 0; kt < 2; ++kt) {
        s8v bv;
        #pragma unroll
        for (int i = 0; i < 8; ++i) bv[i] = (short)f2bf_s(rp[kt][i][l]);
        oa[nt] = __builtin_amdgcn_mfma_f32_16x16x32_bf16(pa[kt], bv, oa[nt], 0, 0, 0);
      }
    }
    size_t base = (size_t)(b * NCH + chunk) * H_;
    #pragma unroll
    for (int nt = 0; nt < 8; ++nt) {
      int l = w * 128 + nt * 16 + l16;
      #pragma unroll
      for (int r = 0; r < 4; ++r) {
        int h = kg * 4 + r;
        acc_part[(base + h) * LOW_ + l] = (unsigned short)f2bf_s(oa[nt][r]);
      }
    }
  }
}

// Combine per-chunk partials: each block = (h, b, cz) handles 8 chunks x 512 l,
// atomicAdd f32 partial into wl. grid (16,8,8) x 128 thr.
__global__ __launch_bounds__(128) void reduce_kernel(
    const float* __restrict__ m_part, const float* __restrict__ l_part,
    const unsigned short* __restrict__ acc_part, float* __restrict__ wl)
{
  int h = blockIdx.x, b = blockIdx.y, cz = blockIdx.z, t = threadIdx.x;
  __shared__ float wli[8];
  if (t < 64) {
    float mc = m_part[(b * NCH + t) * H_ + h];
    float M = mc;
    #pragma unroll
    for (int d = 1; d < 64; d <<= 1) M = fmaxf(M, __shfl_xor(M, d));
    float wc = expf(mc - M);
    float L = l_part[(b * NCH + t) * H_ + h] * wc;
    #pragma unroll
    for (int d = 1; d < 64; d <<= 1) L += __shfl_xor(L, d);
    int rel = t - cz * 8;
    if (rel >= 0 && rel < 8) wli[rel] = wc / L;
  }
  __syncthreads();
  int l0 = t * 4;
  float a0 = 0.f, a1 = 0.f, a2 = 0.f, a3 = 0.f;
  const unsigned short* ap =
      acc_part + ((size_t)(b * NCH + cz * 8) * H_ + h) * LOW_ + l0;
  #pragma unroll
  for (int c = 0; c < 8; ++c) {
    uint2 pk = *(const uint2*)(ap + (size_t)c * H_ * LOW_);
    float wc = wli[c];
    a0 = fmaf(bf2f((unsigned short)(pk.x & 0xffffu)), wc, a0);
    a1 = fmaf(bf2f((unsigned short)(pk.x >> 16)),     wc, a1);
    a2 = fmaf(bf2f((unsigned short)(pk.y & 0xffffu)), wc, a2);
    a3 = fmaf(bf2f((unsigned short)(pk.y >> 16)),     wc, a3);
  }
  float* wp = wl + (size_t)(b * H_ + h) * LOW_ + l0;
  atomicAdd(wp, a0); atomicAdd(wp + 1, a1);
  atomicAdd(wp + 2, a2); atomicAdd(wp + 3, a3);
}

// Project weighted latent through FU's V half. Each block = (h, b, lz):
// 64-l slice, full 128 d; atomicAdd into o_heads. grid (16,8,8) x 128 thr.
__global__ __launch_bounds__(128) void proj_kernel(
    const float* __restrict__ wl, const float* __restrict__ FU,
    float* __restrict__ o_heads)
{
  int h = blockIdx.x, b = blockIdx.y, lz = blockIdx.z, d = threadIdx.x;
  __shared__ float wsh[64];
  if (d < 64) wsh[d] = wl[(b * H_ + h) * LOW_ + lz * 64 + d];
  __syncthreads();
  float a = 0.f;
  const float* fp = FU + (size_t)(lz * 64) * (2 * E_) + E_ + h * HD_ + d;
  #pragma unroll 4
  for (int l = 0; l < 64; ++l)
    a = fmaf(wsh[l], fp[(size_t)l * (2 * E_)], a);
  atomicAdd(&o_heads[(b * H_ + h) * HD_ + d], a);
}

extern "C" void kernel_launch(void* const* d_in, const int* in_sizes, int n_in,
                              void* d_out, int out_size, void* d_ws, size_t ws_size,
                              hipStream_t stream)
{
  const float* x    = (const float*)d_in[0];
  const float* ckvc = (const float*)d_in[1];
  const float* krc  = (const float*)d_in[2];
  const float* Wdq  = (const float*)d_in[3];
  const float* Wuq  = (const float*)d_in[4];
  const float* Wqr  = (const float*)d_in[5];
  const float* Wdkv = (const float*)d_in[6];
  const float* Wkr  = (const float*)d_in[7];
  const float* FU   = (const float*)d_in[8];
  const float* Wo   = (const float*)d_in[9];
  float* out = (float*)d_out;

  char* ws = (char*)d_ws;
  // zeroed prefix (120832 floats):
  float* Cq             = (float*)(ws + 0);        // 65536 B
  float* Qc             = (float*)(ws + 65536);    // 65536 B
  float* qr_pre         = (float*)(ws + 131072);   // 4096 B
  float* ckvn           = (float*)(ws + 135168);   // 16384 B
  float* krn            = (float*)(ws + 151552);   // 4096 B
  float* wl             = (float*)(ws + 155648);   // 262144 B
  float* o_heads        = (float*)(ws + 417792);   // 65536 B  [prefix end 483328]
  unsigned short* qeff  = (unsigned short*)(ws + 483328);  // 131072 B
  float* score_r        = (float*)(ws + 614400);   // 131072 B
  float* m_part         = (float*)(ws + 745472);   // 32768 B
  float* l_part         = (float*)(ws + 778240);   // 32768 B
  unsigned short* accp  = (unsigned short*)(ws + 811008);  // 8388608 B
  float2* tab2          = (float2*)(ws + 9199616); // 2097152 B (total ~11.3 MB)

  // Zero all atomic targets + build rope table
  init_kernel<<<1024, 256, 0, stream>>>((float*)ws, out, tab2);

  // Cq = x@Wdq ; ckv_new = x@Wdkv ; kr_new = x@Wkr
  matvec8<<<dim3(21, 64), 128, 0, stream>>>(x, E_, Wdq, E_, Cq,
                                            Wdkv, LOW_, ckvn, Wkr, HD_, krn);
  // Qc = Cq@Wuq ; qr_pre = Cq@Wqr
  matvec8<<<dim3(17, 64), 128, 0, stream>>>(Cq, E_, Wuq, E_, Qc,
                                            Wqr, HD_, qr_pre,
                                            (const float*)nullptr, 0, (float*)nullptr);
  qeff_rope_kernel<<<dim3(32, 8), 256, 0, stream>>>(Qc, FU, qeff,
                                                    krc, krn, qr_pre, tab2, score_r);
  attn_kernel<<<dim3(64, 8), 256, 0, stream>>>(ckvc, ckvn, qeff, score_r,
                                               accp, m_part, l_part);
  reduce_kernel<<<dim3(16, 8, 8), 128, 0, stream>>>(m_part, l_part, accp, wl);
  proj_kernel<<<dim3(16, 8, 8), 128, 0, stream>>>(wl, FU, o_heads);
  // out = o_heads @ Wo
  matvec8<<<dim3(16, 64), 128, 0, stream>>>(o_heads, E_, Wo, E_, out,
                                            (const float*)nullptr, 0, (float*)nullptr,
                                            (const float*)nullptr, 0, (float*)nullptr);
}